// Round 1
// baseline (278.940 us; speedup 1.0000x reference)
//
#include <hip/hip_runtime.h>

#define H_ 512
#define N_ 32
#define B_ 4
#define L_ 2048
#define LC 128
#define NC 16   // L_/LC

// ---------------- precompute Ad, Bd (bilinear), Ad^LC ----------------
__global__ void precompute_k(const float* __restrict__ log_dt,
                             const float* __restrict__ log_A_real,
                             const float* __restrict__ A_imag,
                             const float* __restrict__ B_ri,
                             float4* __restrict__ AB,
                             float2* __restrict__ AP) {
  int i = blockIdx.x * 256 + threadIdx.x;
  if (i >= H_ * N_) return;
  int h = i >> 5;
  int n = i & 31;
  float dt = expf(log_dt[h]);
  float ar = -expf(log_A_real[i]);
  float ai = A_imag[i];
  float dr = 0.5f * dt * ar;
  float di = 0.5f * dt * ai;
  float omr = 1.0f - dr;
  float inv = 1.0f / (omr * omr + di * di);
  // Ad = (1+dtA)/(1-dtA) = (1 - |dtA|^2 + 2i*Im(dtA)) / |1-dtA|^2
  float adr = (1.0f - dr * dr - di * di) * inv;
  float adi = 2.0f * di * inv;
  float br = B_ri[2 * n];
  float bi = B_ri[2 * n + 1];
  // Bd = dt * Bc * conj(1-dtA) / |1-dtA|^2 ; conj(1-dtA) = (1-dr) + i*di
  float bdr = dt * (br * omr - bi * di) * inv;
  float bdi = dt * (br * di + bi * omr) * inv;
  AB[i] = make_float4(adr, adi, bdr, bdi);
  float pr = adr, pi = adi;
#pragma unroll
  for (int s = 0; s < 7; ++s) {  // 2^7 = 128 = LC
    float qr = pr * pr - pi * pi;
    float qi = 2.0f * pr * pi;
    pr = qr; pi = qi;
  }
  AP[i] = make_float2(pr, pi);
}

// ---------------- transpose x (B,L,H) -> xT (B,H,L) ----------------
__global__ void transpose_k(const float* __restrict__ in, float* __restrict__ out) {
  __shared__ float tile[32][33];
  int b = blockIdx.z;
  int t0 = blockIdx.x * 32;
  int h0 = blockIdx.y * 32;
  int tx = threadIdx.x;   // 32
  int ty = threadIdx.y;   // 8
  const float* src = in + (size_t)b * L_ * H_;
#pragma unroll
  for (int i = 0; i < 32; i += 8)
    tile[ty + i][tx] = src[(size_t)(t0 + ty + i) * H_ + h0 + tx];
  __syncthreads();
  float* dst = out + (size_t)b * H_ * L_;
#pragma unroll
  for (int i = 0; i < 32; i += 8)
    dst[(size_t)(h0 + ty + i) * L_ + t0 + tx] = tile[tx][ty + i];
}

// ---------------- phase 1: local chunk scans (zero init), store final states ----------------
__global__ __launch_bounds__(256) void phase1_k(const float* __restrict__ xT,
                                                const float4* __restrict__ AB,
                                                float2* __restrict__ xend) {
  int tid = blockIdx.x * 256 + threadIdx.x;
  int n = tid & 31;
  int g = tid >> 5;              // (b*H_ + h)*NC + c
  int c = g & (NC - 1);
  int bh = g >> 4;               // NC = 16
  int h = bh & (H_ - 1);
  float4 ab = AB[(h << 5) + n];
  const float* u = xT + (size_t)bh * L_ + c * LC;
  float xr = 0.f, xi = 0.f;
#pragma unroll 8
  for (int k = 0; k < LC; ++k) {
    float uk = u[k];
    float nr = fmaf(ab.x, xr, fmaf(-ab.y, xi, ab.z * uk));
    float ni = fmaf(ab.y, xr, fmaf(ab.x, xi, ab.w * uk));
    xr = nr; xi = ni;
  }
  xend[(size_t)g * 32 + n] = make_float2(xr, xi);
}

// ---------------- phase 2: propagate chunk-boundary states ----------------
__global__ void phase2_k(const float2* __restrict__ xend,
                         const float2* __restrict__ AP,
                         float2* __restrict__ xstart) {
  int tid = blockIdx.x * 256 + threadIdx.x;   // (b*H_+h)*32 + n
  int n = tid & 31;
  int bh = tid >> 5;
  int h = bh & (H_ - 1);
  float2 ap = AP[(h << 5) + n];
  float xr = 0.f, xi = 0.f;
  for (int c = 0; c < NC; ++c) {
    size_t idx = ((size_t)bh * NC + c) * 32 + n;
    xstart[idx] = make_float2(xr, xi);
    float2 e = xend[idx];
    float nr = fmaf(ap.x, xr, fmaf(-ap.y, xi, e.x));
    float ni = fmaf(ap.y, xr, fmaf(ap.x, xi, e.y));
    xr = nr; xi = ni;
  }
}

// ---------------- phase 3: full scan with correct init, emit y (transposed) ----------------
__global__ __launch_bounds__(256) void phase3_k(const float* __restrict__ xT,
                                                const float4* __restrict__ AB,
                                                const float2* __restrict__ Cri,
                                                const float* __restrict__ Dv,
                                                const float2* __restrict__ xstart,
                                                float* __restrict__ yT) {
  int tid = blockIdx.x * 256 + threadIdx.x;
  int n = tid & 31;
  int g = tid >> 5;
  int c = g & (NC - 1);
  int bh = g >> 4;
  int h = bh & (H_ - 1);
  float4 ab = AB[(h << 5) + n];
  float2 cc = Cri[(h << 5) + n];
  float dd = Dv[h];
  const float* u = xT + (size_t)bh * L_ + c * LC;
  float* yo = yT + (size_t)bh * L_ + c * LC;
  float2 xs = xstart[(size_t)g * 32 + n];
  float xr = xs.x, xi = xs.y;
  for (int k0 = 0; k0 < LC; k0 += 32) {
    float ybuf = 0.f;
#pragma unroll
    for (int kk = 0; kk < 32; ++kk) {
      float uk = u[k0 + kk];
      float nr = fmaf(ab.x, xr, fmaf(-ab.y, xi, ab.z * uk));
      float ni = fmaf(ab.y, xr, fmaf(ab.x, xi, ab.w * uk));
      xr = nr; xi = ni;
      float p = fmaf(cc.x, xr, -(cc.y * xi));
      p += __shfl_xor(p, 1);
      p += __shfl_xor(p, 2);
      p += __shfl_xor(p, 4);
      p += __shfl_xor(p, 8);
      p += __shfl_xor(p, 16);
      float yv = fmaf(dd, uk, p);
      if (kk == n) ybuf = yv;   // lane n banks timestep k0+n
    }
    yo[k0 + n] = ybuf;          // coalesced 32-float store per group
  }
}

// ---------------- fused GLU GEMM: out = (y@W1) * sigmoid(y@W2) ----------------
// A is yT in (B,H,L): A[k, m] = yT[b*H*L + k*L + t], m = b*L + t.
#define TM 128
#define TN 64
#define TK 32
__global__ __launch_bounds__(256) void glu_gemm_k(const float* __restrict__ yT,
                                                  const float* __restrict__ W1,
                                                  const float* __restrict__ W2,
                                                  float* __restrict__ out) {
  __shared__ float As[TK][TM];
  __shared__ float B1s[TK][TN];
  __shared__ float B2s[TK][TN];
  int m0 = blockIdx.x * TM;
  int j0 = blockIdx.y * TN;
  int b = m0 >> 11;            // L_ = 2048, TM divides L_ so tile stays in one b
  int t0 = m0 & (L_ - 1);
  int tid = threadIdx.x;
  int tx = tid & 15;
  int ty = tid >> 4;
  const float* Abase = yT + (size_t)b * H_ * L_ + t0;
  float acc1[2][4][4] = {{{0.f}}};
  float acc2[2][4][4] = {{{0.f}}};
  int arow = tid >> 5;          // 0..7
  int acol = (tid & 31) * 4;    // 0..124
  int brow = tid >> 4;          // 0..15
  int bcol = (tid & 15) * 4;    // 0..60
  for (int k0 = 0; k0 < H_; k0 += TK) {
    float4 a[4], w1[2], w2[2];
#pragma unroll
    for (int r = 0; r < 4; ++r)
      a[r] = *(const float4*)(Abase + (size_t)(k0 + arow + r * 8) * L_ + acol);
#pragma unroll
    for (int r = 0; r < 2; ++r) {
      w1[r] = *(const float4*)(W1 + (size_t)(k0 + brow + r * 16) * H_ + j0 + bcol);
      w2[r] = *(const float4*)(W2 + (size_t)(k0 + brow + r * 16) * H_ + j0 + bcol);
    }
    __syncthreads();
#pragma unroll
    for (int r = 0; r < 4; ++r)
      *(float4*)&As[arow + r * 8][acol] = a[r];
#pragma unroll
    for (int r = 0; r < 2; ++r) {
      *(float4*)&B1s[brow + r * 16][bcol] = w1[r];
      *(float4*)&B2s[brow + r * 16][bcol] = w2[r];
    }
    __syncthreads();
#pragma unroll
    for (int k = 0; k < TK; ++k) {
      float4 a0 = *(const float4*)&As[k][tx * 4];
      float4 a1 = *(const float4*)&As[k][64 + tx * 4];
      float4 b1 = *(const float4*)&B1s[k][ty * 4];
      float4 b2 = *(const float4*)&B2s[k][ty * 4];
      float am[2][4] = {{a0.x, a0.y, a0.z, a0.w}, {a1.x, a1.y, a1.z, a1.w}};
      float bv1[4] = {b1.x, b1.y, b1.z, b1.w};
      float bv2[4] = {b2.x, b2.y, b2.z, b2.w};
#pragma unroll
      for (int gg = 0; gg < 2; ++gg)
#pragma unroll
        for (int r = 0; r < 4; ++r)
#pragma unroll
          for (int q = 0; q < 4; ++q) {
            acc1[gg][r][q] = fmaf(am[gg][r], bv1[q], acc1[gg][r][q]);
            acc2[gg][r][q] = fmaf(am[gg][r], bv2[q], acc2[gg][r][q]);
          }
    }
  }
#pragma unroll
  for (int gg = 0; gg < 2; ++gg) {
    int mbase = m0 + gg * 64 + tx * 4;
#pragma unroll
    for (int r = 0; r < 4; ++r) {
      float4 o;
      o.x = acc1[gg][r][0] / (1.0f + __expf(-acc2[gg][r][0]));
      o.y = acc1[gg][r][1] / (1.0f + __expf(-acc2[gg][r][1]));
      o.z = acc1[gg][r][2] / (1.0f + __expf(-acc2[gg][r][2]));
      o.w = acc1[gg][r][3] / (1.0f + __expf(-acc2[gg][r][3]));
      *(float4*)(out + (size_t)(mbase + r) * H_ + j0 + ty * 4) = o;
    }
  }
}

extern "C" void kernel_launch(void* const* d_in, const int* in_sizes, int n_in,
                              void* d_out, int out_size, void* d_ws, size_t ws_size,
                              hipStream_t stream) {
  (void)in_sizes; (void)n_in; (void)out_size; (void)ws_size;
  const float* x          = (const float*)d_in[0];
  const float* log_dt     = (const float*)d_in[1];
  const float* log_A_real = (const float*)d_in[2];
  const float* A_imag     = (const float*)d_in[3];
  const float* B_ri       = (const float*)d_in[4];
  const float* C_ri       = (const float*)d_in[5];
  const float* Dv         = (const float*)d_in[6];
  const float* W1         = (const float*)d_in[7];
  const float* W2         = (const float*)d_in[8];
  float* out = (float*)d_out;
  char* ws = (char*)d_ws;

  float*  xT     = (float*)(ws);                               // 16 MiB
  float*  yT     = (float*)(ws + (16u << 20));                 // 16 MiB
  float4* AB     = (float4*)(ws + (32u << 20));                // 256 KiB
  float2* AP     = (float2*)(ws + (32u << 20) + (256u << 10)); // 128 KiB
  float2* xend   = (float2*)(ws + (33u << 20));                // 8 MiB
  float2* xstart = (float2*)(ws + (41u << 20));                // 8 MiB

  precompute_k<<<(H_ * N_ + 255) / 256, 256, 0, stream>>>(log_dt, log_A_real, A_imag, B_ri, AB, AP);

  dim3 tgrid(L_ / 32, H_ / 32, B_);
  dim3 tblock(32, 8);
  transpose_k<<<tgrid, tblock, 0, stream>>>(x, xT);

  phase1_k<<<(B_ * H_ * NC * 32) / 256, 256, 0, stream>>>(xT, AB, xend);
  phase2_k<<<(B_ * H_ * N_) / 256, 256, 0, stream>>>(xend, AP, xstart);
  phase3_k<<<(B_ * H_ * NC * 32) / 256, 256, 0, stream>>>(xT, AB, (const float2*)C_ri, Dv, xstart, yT);

  dim3 ggrid((B_ * L_) / TM, H_ / TN);
  glu_gemm_k<<<ggrid, 256, 0, stream>>>(yT, W1, W2, out);
}